// Round 13
// baseline (135.600 us; speedup 1.0000x reference)
//
#include <hip/hip_runtime.h>

typedef unsigned int u32;
typedef unsigned short u16;
typedef unsigned long long u64;

typedef __attribute__((ext_vector_type(4))) float f32x4;
typedef __attribute__((ext_vector_type(8))) __bf16 bf16x8;
typedef __attribute__((ext_vector_type(8))) u16 u16x8;
typedef __attribute__((ext_vector_type(4))) u16 u16x4;

#define NB 256
#define ND 512
#define NC 100000
#define NBLK 782               // stripes of 128 cols
#define CAP 131072             // u64 collect entries (1 MB)
#define THRC 0.15f             // collect threshold << neg_th (~0.188)
#define EXP2K 92.33248261689366f   // 64*log2(e)

// ---- ws layout (bytes) ----
#define OFF_EMBN  0            // u16 [256*512] = 262144
#define OFF_TGT   262144       // f32 [256]
#define OFF_SEXP  263168       // f32 [256]
#define OFF_AMAX  264192       // u64 [256] = 2048
#define OFF_SCAL  266240       // u32 [64] {topk, bufcnt, ...}
#define OFF_PART  266496       // f32 [256][800] = 819200
#define OFF_BUF   1085696      // u64 [CAP] = 1048576

__device__ __forceinline__ u32 ordkey(float f) {
  u32 u = __float_as_uint(f);
  return (u & 0x80000000u) ? ~u : (u | 0x80000000u);
}
__device__ __forceinline__ float inv_ordkey(u32 key) {
  u32 u = (key & 0x80000000u) ? (key & 0x7FFFFFFFu) : ~key;
  return __uint_as_float(u);
}
__device__ __forceinline__ u16 f2bf(float x) {  // RNE f32->bf16
  u32 u = __float_as_uint(x);
  return (u16)((u + 0x7FFFu + ((u >> 16) & 1u)) >> 16);
}
__device__ __forceinline__ float bf2f(u16 h) {
  return __uint_as_float(((u32)h) << 16);
}
// B-LDS chunk swizzle (proven R8/R12)
__device__ __forceinline__ int bswz(int n) {
  return (n & 7) ^ ((n >> 3) & 7);
}

typedef const u32 __attribute__((address_space(1)))* gcp;
typedef u32 __attribute__((address_space(3)))* lsp;
__device__ __forceinline__ void gload16(const void* g, void* l) {
  __builtin_amdgcn_global_load_lds((gcp)g, (lsp)l, 16, 0, 0);
}

// ---------------- K0: normalize embedding rows -> bf16 + ws clears ----
__global__ void k_prep(const float* __restrict__ emb, u16* __restrict__ embn,
                       u64* __restrict__ amax_g, u32* __restrict__ scal) {
  __shared__ float s[128];
  const int r = blockIdx.x, t = threadIdx.x;
  float4 v = *(const float4*)(emb + r * ND + t * 4);
  s[t] = v.x * v.x + v.y * v.y + v.z * v.z + v.w * v.w;
  const int gidx = r * 128 + t;
  if (gidx < 256) amax_g[gidx] = 0ull;
  else if (gidx < 320) scal[gidx - 256] = 0u;
  __syncthreads();
  for (int st = 64; st > 0; st >>= 1) { if (t < st) s[t] += s[t + st]; __syncthreads(); }
  const float rinv = 1.0f / sqrtf(s[0]);
  u16x4 o = { f2bf(v.x * rinv), f2bf(v.y * rinv), f2bf(v.z * rinv), f2bf(v.w * rinv) };
  *(u16x4*)(embn + r * ND + t * 4) = o;
}

// ---------------- K1: tg[r] = clip(embn[r].bf16(kern[:,lb]) / ||kern[:,lb]||)
__global__ __launch_bounds__(512) void k_tgt(const float* __restrict__ kern,
                                             const u16* __restrict__ embn,
                                             const int* __restrict__ lab,
                                             float* __restrict__ tgtws) {
  __shared__ float sd[512], sq[512];
  const int r = blockIdx.x, t = threadIdx.x;
  const int lb = lab[r];
  const float x = kern[(size_t)t * NC + lb];
  const float xb = bf2f(f2bf(x));                 // same quantization as GEMM B path
  const float a = bf2f(embn[r * ND + t]);
  sd[t] = a * xb; sq[t] = x * x;
  __syncthreads();
  for (int st = 256; st > 0; st >>= 1) {
    if (t < st) { sd[t] += sd[t + st]; sq[t] += sq[t + st]; }
    __syncthreads();
  }
  if (t == 0) {
    float v = sd[0] / sqrtf(sq[0]);
    tgtws[r] = fminf(fmaxf(v, -1.0f), 1.0f);
  }
}

// ---------------- K2: FUSED bf16 MFMA GEMM, small-block edition -------
// tile M=128 x N=128, BK=64, 256 thr = 4 waves (2Mx2N), wave 64x64,
// acc[4][4]. Same per-thread resources as R12 but 4 independent
// blocks/CU (vs 2) -> finer anti-phasing -> higher memory duty cycle.
// B: 8x float4 (4 cols x 8 k-rows, 2KB/wave segs) -> reg transpose ->
// 4x b128 swizzled LDS writes. A: gload_lds(16B) XOR-preswizzled.
// Grid 1568 = 784 stripes x 2 M-halves; mapping keeps both M-halves of
// a stripe temporally adjacent on the SAME XCD (L2 merge of B reads).
__global__ __launch_bounds__(256, 4) void k_gemm(const float* __restrict__ kern,
                                                 const u16* __restrict__ embn,
                                                 const int* __restrict__ lab,
                                                 const float* __restrict__ tgtws,
                                                 u32* __restrict__ scal,
                                                 u64* __restrict__ buf,
                                                 u64* __restrict__ amax_g,
                                                 float* __restrict__ sexp_part) {
  __shared__ u16 As[128 * 64];        // [m][k] linear (source-swizzled)
  __shared__ u16 Bs[128 * 64];        // [n][k] chunk-swizzled
  __shared__ float colp[8][128];      // column ssq partials (k-oct rows)
  __shared__ float sexp_pair[2][128]; // per n-half partials (deterministic)
  __shared__ u64 amax_lds[128];
  __shared__ u32 swcnt[4];
  const int tid = threadIdx.x;
  const int lane = tid & 63;
  const int w = tid >> 6;                     // wave 0..3
  const int mbase = (w >> 1) * 64, nbase = (w & 1) * 64;
  const int l15 = lane & 15, g = lane >> 4;
  // XCD-chunked, M-half-paired block mapping:
  const int bid = blockIdx.x;
  const int x8 = bid & 7, g8 = bid >> 3;      // XCD class, sequence on XCD
  const int mhalf = g8 & 1, pg = g8 >> 1;     // M-half, stripe-in-chunk
  const int p = x8 * 98 + pg;                 // stripe 0..783
  if (p >= NBLK) return;                      // 2 pad stripes (whole block)
  const int cblk = p * 128;
  const int rbase = mhalf * 128;

  if (tid < 128) amax_lds[tid] = 0ull;

  f32x4 acc[4][4];
  #pragma unroll
  for (int i = 0; i < 4; ++i)
    #pragma unroll
    for (int j = 0; j < 4; ++j) acc[i][j] = (f32x4){0.f, 0.f, 0.f, 0.f};

  // A staging: slot = i*256+tid -> row = rbase + (tid>>3) + i*32, chunk = tid&7
  const int sx = ((tid & 7) ^ ((tid >> 3) & 7)) * 8;   // source pre-swizzle
  const u16* a_src[4];
  #pragma unroll
  for (int i = 0; i < 4; ++i)
    a_src[i] = embn + (size_t)(rbase + (tid >> 3) + i * 32) * ND + sx;

  // B staging: thread -> (4 cols nc4.., k-oct ko); 8x float4 loads
  const int nc4 = (tid & 31) * 4, ko = tid >> 5;       // ko 0..7
  int gc4 = cblk + nc4;
  if (gc4 > NC - 4) gc4 = NC - 4;                      // clamp; masked later
  u16* bdst[4];
  #pragma unroll
  for (int i = 0; i < 4; ++i)
    bdst[i] = Bs + (nc4 + i) * 64 + (ko ^ bswz(nc4 + i)) * 8;
  float ss0 = 0.f, ss1 = 0.f, ss2 = 0.f, ss3 = 0.f;

  for (int ks = 0; ks < 8; ++ks) {
    const int k0 = ks * 64;
    // B: 8 x float4 (4 cols x 8 consecutive k-rows; 2KB/wave segments)
    float4 f[8];
    #pragma unroll
    for (int j = 0; j < 8; ++j)
      f[j] = *(const float4*)(kern + (size_t)(k0 + ko * 8 + j) * NC + gc4);
    // A: 4 x global_load_lds(16B)
    #pragma unroll
    for (int i = 0; i < 4; ++i) gload16(a_src[i] + k0, As + i * 2048 + w * 512);
    // B: in-register transpose + convert + ssq + 4 x b128 LDS writes
    ss0 += f[0].x*f[0].x + f[1].x*f[1].x + f[2].x*f[2].x + f[3].x*f[3].x
         + f[4].x*f[4].x + f[5].x*f[5].x + f[6].x*f[6].x + f[7].x*f[7].x;
    ss1 += f[0].y*f[0].y + f[1].y*f[1].y + f[2].y*f[2].y + f[3].y*f[3].y
         + f[4].y*f[4].y + f[5].y*f[5].y + f[6].y*f[6].y + f[7].y*f[7].y;
    ss2 += f[0].z*f[0].z + f[1].z*f[1].z + f[2].z*f[2].z + f[3].z*f[3].z
         + f[4].z*f[4].z + f[5].z*f[5].z + f[6].z*f[6].z + f[7].z*f[7].z;
    ss3 += f[0].w*f[0].w + f[1].w*f[1].w + f[2].w*f[2].w + f[3].w*f[3].w
         + f[4].w*f[4].w + f[5].w*f[5].w + f[6].w*f[6].w + f[7].w*f[7].w;
    u16x8 q0, q1, q2, q3;
    #pragma unroll
    for (int j = 0; j < 8; ++j) {
      q0[j] = f2bf(f[j].x); q1[j] = f2bf(f[j].y);
      q2[j] = f2bf(f[j].z); q3[j] = f2bf(f[j].w);
    }
    *(u16x8*)bdst[0] = q0; *(u16x8*)bdst[1] = q1;
    *(u16x8*)bdst[2] = q2; *(u16x8*)bdst[3] = q3;
    __syncthreads();                       // tiles ready
    #pragma unroll
    for (int kf = 0; kf < 2; ++kf) {
      bf16x8 bfr[4], afr[4];
      #pragma unroll
      for (int nf = 0; nf < 4; ++nf) {
        const int n = nbase + nf * 16 + l15;
        bfr[nf] = *(const bf16x8*)(Bs + n * 64 + (((kf * 4 + g) ^ bswz(n)) * 8));
      }
      #pragma unroll
      for (int mf = 0; mf < 4; ++mf) {
        const int m = mbase + mf * 16 + l15;
        afr[mf] = *(const bf16x8*)(As + m * 64 + ((kf * 32 + g * 8) ^ ((m & 7) << 3)));
      }
      #pragma unroll
      for (int mf = 0; mf < 4; ++mf)
        #pragma unroll
        for (int nf = 0; nf < 4; ++nf)
          acc[mf][nf] = __builtin_amdgcn_mfma_f32_16x16x32_bf16(afr[mf], bfr[nf], acc[mf][nf], 0, 0, 0);
    }
    __syncthreads();                       // protect LDS before re-stage
  }

  // column ssq partials + deterministic reduce (8 k-octs -> 1)
  colp[ko][nc4 + 0] = ss0; colp[ko][nc4 + 1] = ss1;
  colp[ko][nc4 + 2] = ss2; colp[ko][nc4 + 3] = ss3;
  __syncthreads();
  if (tid < 128) {
    float s = ((colp[0][tid] + colp[1][tid]) + (colp[2][tid] + colp[3][tid]))
            + ((colp[4][tid] + colp[5][tid]) + (colp[6][tid] + colp[7][tid]));
    colp[0][tid] = s;
  }
  __syncthreads();

  // ---- fused epilogue: stats straight from accumulators ----
  float cinv[4];
  #pragma unroll
  for (int nf = 0; nf < 4; ++nf) {
    const int nl = nbase + nf * 16 + l15;
    cinv[nf] = ((cblk + nl) < NC) ? (1.0f / sqrtf(colp[0][nl])) : 0.f;
  }
  u32 cnt_t = 0;
  #pragma unroll
  for (int mf = 0; mf < 4; ++mf) {
    #pragma unroll
    for (int r = 0; r < 4; ++r) {
      const int rloc = mbase + mf * 16 + g * 4 + r;
      const int rglob = rbase + rloc;
      const float tg = tgtws[rglob];
      const int lb = lab[rglob];
      float e = 0.f; u64 pk = 0ull;
      #pragma unroll
      for (int nf = 0; nf < 4; ++nf) {
        const int c = cblk + nbase + nf * 16 + l15;
        if (c < NC) {
          float v = acc[mf][nf][r] * cinv[nf];
          v = fminf(fmaxf(v, -1.0f), 1.0f);
          e += exp2f(EXP2K * v);
          const u64 pq = ((u64)ordkey(v) << 32) | (u32)(0xFFFFFFFFu - (u32)c);
          if (pq > pk) pk = pq;
          if (c != lb) {
            if (v > tg) cnt_t++;
            else if (v >= THRC) {
              u32 pos = atomicAdd(&scal[1], 1u);
              if (pos < CAP) buf[pos] = ((u64)ordkey(v) << 32) | (u32)rglob;
            }
          }
        }
      }
      #pragma unroll
      for (int m = 1; m < 16; m <<= 1) {
        e += __shfl_xor(e, m, 64);
        u64 o = __shfl_xor(pk, m, 64);
        if (o > pk) pk = o;
      }
      if (l15 == 0) {
        sexp_pair[w & 1][rloc] = e;         // each (half,rloc) written once
        atomicMax(&amax_lds[rloc], pk);     // integer max: order-independent
      }
    }
  }
  #pragma unroll
  for (int m = 1; m < 64; m <<= 1) cnt_t += __shfl_xor(cnt_t, m, 64);
  if (lane == 0) swcnt[w] = cnt_t;
  __syncthreads();
  if (tid == 0) {
    atomicAdd(&scal[0], ((swcnt[0] + swcnt[1]) + (swcnt[2] + swcnt[3])));
  }
  if (tid < 128) {
    sexp_part[(size_t)(rbase + tid) * 800 + p] = sexp_pair[0][tid] + sexp_pair[1][tid];
    atomicMax(&amax_g[rbase + tid], amax_lds[tid]);
  }
}

// ---------------- K3: deterministic per-row sexp reduction ------------
__global__ void k_reduce(const float* __restrict__ part, float* __restrict__ sexpws) {
  __shared__ float s[256];
  const int r = blockIdx.x, t = threadIdx.x;
  float a = 0.f;
  for (int b = t; b < NBLK; b += 256) a += part[(size_t)r * 800 + b];
  s[t] = a;
  __syncthreads();
  for (int st = 128; st > 0; st >>= 1) { if (t < st) s[t] += s[t + st]; __syncthreads(); }
  if (t == 0) sexpws[r] = s[0];
}

// ---------------- K4: finisher (1 block): select th + stats + loss ----
__global__ __launch_bounds__(1024) void k_finish(const u64* __restrict__ buf,
                                                 const u32* __restrict__ scal,
                                                 const int* __restrict__ lab,
                                                 const float* __restrict__ tgtws,
                                                 const float* __restrict__ sexpws,
                                                 const u64* __restrict__ amax_g,
                                                 float* __restrict__ out) {
  __shared__ u32 hist[4096];
  __shared__ u32 s[1024], cs[1024];
  __shared__ u32 sb1, sr1, sb2, sr2, sthkey, lcnt;
  __shared__ u64 lbuf[512];
  __shared__ float rl[256], ra[256];
  const int tid = threadIdx.x;
  const int n = (int)min(scal[1], (u32)CAP);
  const int topk = (int)scal[0];
  int a = 25599744 - topk; if (a < 0) a = 0;               // B*(C-1)
  int k = (int)ceilf((1.0f / 99999.0f) * (float)a);        // mirror ref f32 math
  if (k < 1) k = 1;

  if (tid == 0) { sb1 = 0; sr1 = 1; sb2 = 0; sr2 = 1; lcnt = 0; }
  // ---- level 1: key bits 31..20 ----
  for (int i = tid; i < 4096; i += 1024) hist[i] = 0;
  __syncthreads();
  for (int i = tid; i < n; i += 1024) atomicAdd(&hist[(u32)(buf[i] >> 52)], 1u);
  __syncthreads();
  {
    u32 h[4]; u32 c = 0;
    #pragma unroll
    for (int j = 0; j < 4; ++j) { h[j] = hist[tid * 4 + j]; c += h[j]; }
    cs[tid] = c; s[tid] = c;
    __syncthreads();
    for (int off = 1; off < 1024; off <<= 1) {
      u32 v = (tid + off < 1024) ? s[tid + off] : 0u;
      __syncthreads(); s[tid] += v; __syncthreads();
    }
    u32 incl = s[tid], excl = incl - cs[tid];
    if ((int)excl < k && (int)incl >= k) {
      u32 cum = excl;
      for (int j = 3; j >= 0; --j) {
        cum += h[j];
        if ((int)cum >= k) { sb1 = tid * 4 + j; sr1 = (u32)k - (cum - h[j]); break; }
      }
    }
  }
  __syncthreads();
  const u32 b1 = sb1, r1 = sr1;
  // ---- level 2: key bits 19..8 ----
  for (int i = tid; i < 4096; i += 1024) hist[i] = 0;
  __syncthreads();
  for (int i = tid; i < n; i += 1024) {
    u32 key = (u32)(buf[i] >> 32);
    if ((key >> 20) == b1) atomicAdd(&hist[(key >> 8) & 4095u], 1u);
  }
  __syncthreads();
  {
    u32 h[4]; u32 c = 0;
    #pragma unroll
    for (int j = 0; j < 4; ++j) { h[j] = hist[tid * 4 + j]; c += h[j]; }
    cs[tid] = c; s[tid] = c;
    __syncthreads();
    for (int off = 1; off < 1024; off <<= 1) {
      u32 v = (tid + off < 1024) ? s[tid + off] : 0u;
      __syncthreads(); s[tid] += v; __syncthreads();
    }
    u32 incl = s[tid], excl = incl - cs[tid];
    if (excl < r1 && incl >= r1) {
      u32 cum = excl;
      for (int j = 3; j >= 0; --j) {
        cum += h[j];
        if (cum >= r1) { sb2 = tid * 4 + j; sr2 = r1 - (cum - h[j]); break; }
      }
    }
  }
  __syncthreads();
  const u32 b2 = sb2, r2 = sr2;
  // ---- level 3: key bits 7..0 ----
  for (int i = tid; i < 256; i += 1024) hist[i] = 0;
  __syncthreads();
  const u32 pfx = (b1 << 12) | b2;
  for (int i = tid; i < n; i += 1024) {
    u32 key = (u32)(buf[i] >> 32);
    if ((key >> 8) == pfx) atomicAdd(&hist[key & 255u], 1u);
  }
  __syncthreads();
  if (tid == 0) {
    u32 cum = 0, b3 = 0;
    for (int j = 255; j >= 0; --j) { cum += hist[j]; if (cum >= r2) { b3 = (u32)j; break; } }
    sthkey = (b1 << 20) | (b2 << 8) | b3;
  }
  __syncthreads();
  const u32 thk = sthkey;
  // ---- collect strictly-greater entries (k-1 < 512 of them) ----
  for (int i = tid; i < n; i += 1024) {
    u64 e = buf[i];
    if ((u32)(e >> 32) > thk) { u32 pq = atomicAdd(&lcnt, 1u); if (pq < 512) lbuf[pq] = e; }
  }
  __syncthreads();
  const int m = (int)min(lcnt, 512u);
  if (tid < 256) {
    const int r = tid;
    int cnt = 0; float ssq = 0.f;
    for (int j = 0; j < m; ++j) {
      u64 e = lbuf[j];
      if ((u32)(e & 0xFFFFFFFFu) == (u32)r) {
        float v = inv_ordkey((u32)(e >> 32));
        cnt++; ssq += v * v;
      }
    }
    const float tg = tgtws[r];
    const float times = fmaxf((float)cnt, 1.0f);
    const float nm = ssq / times;
    const float tgm = (tg - 0.4f) - (1.0f + tg) * nm;
    const float sexp = sexpws[r] - exp2f(EXP2K * tg) + exp2f(EXP2K * tgm);
    rl[r] = logf(sexp) - 64.0f * tgm;
    const u32 acol = 0xFFFFFFFFu - (u32)(amax_g[r] & 0xFFFFFFFFu);
    ra[r] = (acol == (u32)lab[r]) ? 1.0f : 0.0f;
  }
  __syncthreads();
  for (int st = 128; st > 0; st >>= 1) {
    if (tid < st) { rl[tid] += rl[tid + st]; ra[tid] += ra[tid + st]; }
    __syncthreads();
  }
  if (tid == 0) { out[0] = rl[0] * (1.0f / 256.0f); out[1] = ra[0] * (1.0f / 256.0f); }
}

extern "C" void kernel_launch(void* const* d_in, const int* in_sizes, int n_in,
                              void* d_out, int out_size, void* d_ws, size_t ws_size,
                              hipStream_t stream) {
  const float* emb = (const float*)d_in[0];
  const int* lab = (const int*)d_in[1];
  const float* kern = (const float*)d_in[2];
  float* out = (float*)d_out;
  char* ws = (char*)d_ws;

  u16* embn = (u16*)(ws + OFF_EMBN);
  float* tgtws = (float*)(ws + OFF_TGT);
  float* sexpws = (float*)(ws + OFF_SEXP);
  u64* amax_g = (u64*)(ws + OFF_AMAX);
  u32* scal = (u32*)(ws + OFF_SCAL);   // [0]=topk [1]=bufcnt
  float* part = (float*)(ws + OFF_PART);
  u64* buf = (u64*)(ws + OFF_BUF);

  k_prep<<<NB, 128, 0, stream>>>(emb, embn, amax_g, scal);
  k_tgt<<<NB, 512, 0, stream>>>(kern, embn, lab, tgtws);
  k_gemm<<<1568, 256, 0, stream>>>(kern, embn, lab, tgtws, scal, buf, amax_g, part);
  k_reduce<<<NB, 256, 0, stream>>>(part, sexpws);
  k_finish<<<1, 1024, 0, stream>>>(buf, scal, lab, tgtws, sexpws, amax_g, out);
}